// Round 2
// baseline (24763.048 us; speedup 1.0000x reference)
//
#include <hip/hip_runtime.h>

typedef unsigned short u16;
typedef __bf16 bf16x8 __attribute__((ext_vector_type(8)));
typedef float f32x4 __attribute__((ext_vector_type(4)));

__device__ __forceinline__ u16 f2b(float f) {
  unsigned u = __float_as_uint(f);
  return (u16)((u + 0x7fffu + ((u >> 16) & 1u)) >> 16);
}
__device__ __forceinline__ float b2f(u16 h) {
  return __uint_as_float(((unsigned)h) << 16);
}

// ---------------- generic fp32 -> bf16 cast ----------------
__global__ void cast_f32_bf16(const float* __restrict__ in, u16* __restrict__ out, int n) {
  int i = blockIdx.x * 256 + threadIdx.x;
  if (i < n) out[i] = f2b(in[i]);
}

// ---------------- device-wide barrier (arrival counter + broadcast flag) ----------------
__device__ __forceinline__ void grid_bar(unsigned* cnt, unsigned* flag, unsigned ep) {
  __syncthreads();
  if (threadIdx.x == 0) {
    unsigned arrived = __hip_atomic_fetch_add(cnt, 1u, __ATOMIC_ACQ_REL, __HIP_MEMORY_SCOPE_AGENT) + 1u;
    unsigned target = ep * gridDim.x;
    if (arrived == target) {
      __hip_atomic_store(flag, ep, __ATOMIC_RELEASE, __HIP_MEMORY_SCOPE_AGENT);
    } else {
      while (__hip_atomic_load(flag, __ATOMIC_ACQUIRE, __HIP_MEMORY_SCOPE_AGENT) < ep) {
        __builtin_amdgcn_s_sleep(2);
      }
    }
  }
  __syncthreads();
}

// ---------------- tiled bf16 GEMM: C[M,N] = A[M,K] @ B[N,K]^T ----------------
// mode 0: Cf[m*N+n] = acc (+bias[n])         (fp32 out)
// mode 1: Cb[(m&511)*32768 + (m>>9)*1024 + n] = bf16(acc)   (gates layout [t][b][n])
__global__ __launch_bounds__(256) void gemm_bt(
    const u16* __restrict__ A, const u16* __restrict__ B,
    int M, int N, int K,
    const float* __restrict__ bias,
    float* __restrict__ Cf, u16* __restrict__ Cb, int mode)
{
  __shared__ u16 a_sm[128 * 32];
  __shared__ u16 b_sm[128 * 32];
  const int tid = threadIdx.x;
  const int lane = tid & 63;
  const int wid = tid >> 6;
  const int wm = wid >> 1, wn = wid & 1;
  const int m0 = blockIdx.x * 128, n0 = blockIdx.y * 128;
  const int q = lane >> 4, l15 = lane & 15, l3 = lane & 3;

  f32x4 acc[4][4];
  #pragma unroll
  for (int i = 0; i < 4; ++i)
    #pragma unroll
    for (int j = 0; j < 4; ++j) acc[i][j] = (f32x4){0.f, 0.f, 0.f, 0.f};

  for (int kk = 0; kk < K; kk += 32) {
    __syncthreads();
    #pragma unroll
    for (int p = 0; p < 2; ++p) {
      int idx = p * 256 + tid;
      int r = idx >> 2, cch = idx & 3;
      // XOR swizzle on the 16B chunk index to break bank-conflict strides
      *(uint4*)&a_sm[r * 32 + ((cch ^ (r & 3)) * 8)] =
          *(const uint4*)&A[(size_t)(m0 + r) * K + kk + cch * 8];
      *(uint4*)&b_sm[r * 32 + ((cch ^ (r & 3)) * 8)] =
          *(const uint4*)&B[(size_t)(n0 + r) * K + kk + cch * 8];
    }
    __syncthreads();
    bf16x8 af[4], bfr[4];
    #pragma unroll
    for (int s = 0; s < 4; ++s) {
      int ra = wm * 64 + s * 16 + l15;
      af[s] = *(const bf16x8*)&a_sm[ra * 32 + ((q ^ l3) * 8)];
      int rb = wn * 64 + s * 16 + l15;
      bfr[s] = *(const bf16x8*)&b_sm[rb * 32 + ((q ^ l3) * 8)];
    }
    #pragma unroll
    for (int si = 0; si < 4; ++si)
      #pragma unroll
      for (int sj = 0; sj < 4; ++sj)
        acc[si][sj] = __builtin_amdgcn_mfma_f32_16x16x32_bf16(af[si], bfr[sj], acc[si][sj], 0, 0, 0);
  }

  #pragma unroll
  for (int si = 0; si < 4; ++si)
    #pragma unroll
    for (int sj = 0; sj < 4; ++sj)
      #pragma unroll
      for (int e = 0; e < 4; ++e) {
        int m = m0 + wm * 64 + si * 16 + q * 4 + e;
        int n = n0 + wn * 64 + sj * 16 + l15;
        float v = acc[si][sj][e];
        if (mode == 0) {
          if (bias) v += bias[n];
          Cf[(size_t)m * N + n] = v;
        } else {
          Cb[(size_t)(m & 511) * 32768 + (size_t)(m >> 9) * 1024 + n] = f2b(v);
        }
      }
}

// ---------------- persistent GRU layer: 512 steps, 2 device barriers/step ----------------
// grid = 128 workgroups; wg s owns output slice n in [8s, 8s+8).
// LDS holds Whz/Whr rows (zr tile, 16 rows: 8 z + 8 r) and Whg rows (8), ~50.6 KB.
// Phase 1 (waves 0,1): zr-combined MFMA (M=16 batches/wave, N=16 = [z|r] x 8, K=1024),
//   z -> LDS, r*h -> global bf16. Phase 2: g MFMA over (r.h), then h' update.
__global__ __launch_bounds__(256, 1) void gru_layer(
    const u16* __restrict__ Wh,                      // [3][1024][1024] bf16 (z,r,g)
    const float* __restrict__ bz, const float* __restrict__ br, const float* __restrict__ bg,
    const u16* __restrict__ gz, const u16* __restrict__ gr, const u16* __restrict__ gg, // [512][32][1024]
    const float* __restrict__ h0,                    // + l*1024, batch stride 2048
    float* __restrict__ h32, u16* __restrict__ hb, u16* __restrict__ rhb, // 32x1024 each
    u16* __restrict__ seq,                           // [32][512][1024] bf16
    float* __restrict__ hT,                          // + l*1024, batch stride 2048
    unsigned* __restrict__ cnt, unsigned* __restrict__ flag)
{
  constexpr int WSTR = 1032;                          // 1024 + 8 pad (2064 B rows: 2-way banks, free)
  __shared__ u16 zr_w[16 * WSTR];
  __shared__ u16 g_w[8 * WSTR];
  __shared__ float z_sm[32 * 8];

  const int tid = threadIdx.x;
  const int lane = tid & 63;
  const int wid = tid >> 6;
  const int slice = blockIdx.x;                       // 0..127
  const int nb = slice * 8;

  // stage weight rows into LDS (once per layer): 24 rows x 128 uint4-chunks
  for (int idx = tid; idx < 24 * 128; idx += 256) {
    int r = idx >> 7;
    int c = idx & 127;
    int gate, lr; u16* dst;
    if (r < 16) { gate = r >> 3; lr = r & 7; dst = &zr_w[r * WSTR + c * 8]; }
    else        { gate = 2;      lr = r - 16; dst = &g_w[lr * WSTR + c * 8]; }
    const u16* src = Wh + (size_t)gate * 1048576 + (size_t)(nb + lr) * 1024 + c * 8;
    *(uint4*)dst = *(const uint4*)src;
  }
  // init h state (each wg initializes a distinct 256-element span)
  {
    int i = blockIdx.x * 256 + tid;                   // 0..32767
    int b = i >> 10, n = i & 1023;
    float v = h0[b * 2048 + n];
    h32[i] = v;
    hb[i] = f2b(v);
  }
  unsigned ep = 0;
  grid_bar(cnt, flag, ++ep);

  const int q = lane >> 4;
  const int c15 = lane & 15;

  for (int t = 0; t < 512; ++t) {
    // ---------- phase 1: z, r ----------
    if (wid < 2) {
      f32x4 acc = {0.f, 0.f, 0.f, 0.f};
      const int arow = wid * 16 + c15;                // batch for A fragment
      const bf16x8* ap = (const bf16x8*)(hb + arow * 1024);
      const u16* bp = &zr_w[c15 * WSTR + q * 8];      // B row: 0-7 = z slice, 8-15 = r slice
      #pragma unroll 8
      for (int ks = 0; ks < 32; ++ks) {
        bf16x8 af = ap[ks * 4 + q];
        bf16x8 bf = *(const bf16x8*)(bp + ks * 32);
        acc = __builtin_amdgcn_mfma_f32_16x16x32_bf16(af, bf, acc, 0, 0, 0);
      }
      const int nl = c15 & 7;
      const int n = nb + nl;
      const bool isr = c15 >= 8;
      const u16* gin = (isr ? gr : gz) + (size_t)t * 32768 + n;
      const float bias = isr ? br[n] : bz[n];
      #pragma unroll
      for (int e = 0; e < 4; ++e) {
        int b = wid * 16 + q * 4 + e;                 // D row = batch
        float pre = acc[e] + bias + b2f(gin[b * 1024]);
        float s = 1.f / (1.f + __expf(-pre));
        if (isr) {
          float ho = h32[b * 1024 + n];
          rhb[b * 1024 + n] = f2b(s * ho);
        } else {
          z_sm[b * 8 + nl] = s;
        }
      }
    }
    grid_bar(cnt, flag, ++ep);
    // ---------- phase 2: g, h' ----------
    if (wid < 2) {
      f32x4 acc = {0.f, 0.f, 0.f, 0.f};
      const int arow = wid * 16 + c15;
      const bf16x8* ap = (const bf16x8*)(rhb + arow * 1024);
      const u16* bp = &g_w[(c15 & 7) * WSTR + q * 8]; // lanes 8-15 duplicate rows 0-7 (broadcast)
      #pragma unroll 8
      for (int ks = 0; ks < 32; ++ks) {
        bf16x8 af = ap[ks * 4 + q];
        bf16x8 bf = *(const bf16x8*)(bp + ks * 32);
        acc = __builtin_amdgcn_mfma_f32_16x16x32_bf16(af, bf, acc, 0, 0, 0);
      }
      if (c15 < 8) {
        const int n = nb + c15;
        const float bias = bg[n];
        const u16* gin = gg + (size_t)t * 32768 + n;
        #pragma unroll
        for (int e = 0; e < 4; ++e) {
          int b = wid * 16 + q * 4 + e;
          float pre = acc[e] + bias + b2f(gin[b * 1024]);
          float ex = __expf(2.f * pre);
          float gv = 1.f - 2.f / (ex + 1.f);          // tanh, overflow-safe both ends
          float z = z_sm[b * 8 + c15];
          float ho = h32[b * 1024 + n];
          float hn = z * ho + (1.f - z) * gv;
          h32[b * 1024 + n] = hn;
          hb[b * 1024 + n] = f2b(hn);
          seq[(size_t)(b * 512 + t) * 1024 + n] = f2b(hn);
          if (t == 511) hT[b * 2048 + n] = hn;
        }
      }
    }
    grid_bar(cnt, flag, ++ep);
  }
}

// ---------------- host ----------------
extern "C" void kernel_launch(void* const* d_in, const int* in_sizes, int n_in,
                              void* d_out, int out_size, void* d_ws, size_t ws_size,
                              hipStream_t stream) {
  (void)in_sizes; (void)n_in; (void)out_size; (void)ws_size;
  char* ws = (char*)d_ws;
  const size_t MB = 1024ull * 1024ull;
  u16* gz   = (u16*)(ws + 0);
  u16* gr   = (u16*)(ws + 32 * MB);
  u16* gg   = (u16*)(ws + 64 * MB);
  u16* seq0 = (u16*)(ws + 96 * MB);
  u16* seq1 = (u16*)(ws + 128 * MB);
  u16* xb   = (u16*)(ws + 160 * MB);
  u16* Wh0  = (u16*)(ws + 164 * MB);
  u16* Wh1  = (u16*)(ws + 170 * MB);
  u16* Wx0  = (u16*)(ws + 176 * MB);
  u16* Wx1  = (u16*)(ws + 177 * MB);
  u16* Wyb  = (u16*)(ws + 183 * MB);
  float* h32 = (float*)(ws + 184 * MB);
  u16* hb   = (u16*)(ws + 184 * MB + 128 * 1024);
  u16* rhb  = (u16*)(ws + 184 * MB + 192 * 1024);
  unsigned* sync = (unsigned*)(ws + 184 * MB + 256 * 1024);
  // sync[0]=cnt0, sync[16]=flag0, sync[32]=cnt1, sync[48]=flag1 (separate cachelines)

  hipMemsetAsync(sync, 0, 64 * sizeof(unsigned), stream);

  auto cast = [&](const void* in, u16* out, int n) {
    cast_f32_bf16<<<(n + 255) / 256, 256, 0, stream>>>((const float*)in, out, n);
  };
  cast(d_in[0], xb, 2097152);                               // x
  cast(d_in[3],  Wh0 + 0,       1048576);                   // Whz0
  cast(d_in[6],  Wh0 + 1048576, 1048576);                   // Whr0
  cast(d_in[9],  Wh0 + 2097152, 1048576);                   // Whg0
  cast(d_in[12], Wh1 + 0,       1048576);                   // Whz1
  cast(d_in[15], Wh1 + 1048576, 1048576);                   // Whr1
  cast(d_in[18], Wh1 + 2097152, 1048576);                   // Whg1
  cast(d_in[2],  Wx0 + 0,      131072);                     // Wxz0
  cast(d_in[5],  Wx0 + 131072, 131072);                     // Wxr0
  cast(d_in[8],  Wx0 + 262144, 131072);                     // Wxg0
  cast(d_in[11], Wx1 + 0,       1048576);                   // Wxz1
  cast(d_in[14], Wx1 + 1048576, 1048576);                   // Wxr1
  cast(d_in[17], Wx1 + 2097152, 1048576);                   // Wxg1
  cast(d_in[20], Wyb, 131072);                              // Wy

  dim3 blk(256);
  dim3 gP(128, 8);
  // layer-0 input projections (M=16384, N=1024, K=128) -> gates [t][b][n] bf16
  gemm_bt<<<gP, blk, 0, stream>>>(xb, Wx0 + 0,      16384, 1024, 128, nullptr, nullptr, gz, 1);
  gemm_bt<<<gP, blk, 0, stream>>>(xb, Wx0 + 131072, 16384, 1024, 128, nullptr, nullptr, gr, 1);
  gemm_bt<<<gP, blk, 0, stream>>>(xb, Wx0 + 262144, 16384, 1024, 128, nullptr, nullptr, gg, 1);

  float* y_out = (float*)d_out;
  float* hid = y_out + 2097152;                             // hidden (32,2,1024)

  gru_layer<<<128, blk, 0, stream>>>(Wh0,
      (const float*)d_in[4], (const float*)d_in[7], (const float*)d_in[10],
      gz, gr, gg, (const float*)d_in[1] + 0,
      h32, hb, rhb, seq0, hid + 0, sync + 0, sync + 16);

  // layer-1 input projections (K=1024)
  gemm_bt<<<gP, blk, 0, stream>>>(seq0, Wx1 + 0,       16384, 1024, 1024, nullptr, nullptr, gz, 1);
  gemm_bt<<<gP, blk, 0, stream>>>(seq0, Wx1 + 1048576, 16384, 1024, 1024, nullptr, nullptr, gr, 1);
  gemm_bt<<<gP, blk, 0, stream>>>(seq0, Wx1 + 2097152, 16384, 1024, 1024, nullptr, nullptr, gg, 1);

  gru_layer<<<128, blk, 0, stream>>>(Wh1,
      (const float*)d_in[13], (const float*)d_in[16], (const float*)d_in[19],
      gz, gr, gg, (const float*)d_in[1] + 1024,
      h32, hb, rhb, seq1, hid + 1024, sync + 32, sync + 48);

  // output projection y = seq1 @ Wy^T + by  (M=16384, N=128, K=1024), fp32 out
  dim3 gY(128, 1);
  gemm_bt<<<gY, blk, 0, stream>>>(seq1, Wyb, 16384, 128, 1024, (const float*)d_in[21], y_out, nullptr, 0);
}

// Round 3
// 21405.026 us; speedup vs baseline: 1.1569x; 1.1569x over previous
//
#include <hip/hip_runtime.h>

typedef unsigned short u16;
typedef __bf16 bf16x8 __attribute__((ext_vector_type(8)));
typedef float f32x4 __attribute__((ext_vector_type(4)));

__device__ __forceinline__ u16 f2b(float f) {
  unsigned u = __float_as_uint(f);
  return (u16)((u + 0x7fffu + ((u >> 16) & 1u)) >> 16);
}
__device__ __forceinline__ float b2f(u16 h) {
  return __uint_as_float(((unsigned)h) << 16);
}

// ---------------- generic fp32 -> bf16 cast ----------------
__global__ void cast_f32_bf16(const float* __restrict__ in, u16* __restrict__ out, int n) {
  int i = blockIdx.x * 256 + threadIdx.x;
  if (i < n) out[i] = f2b(in[i]);
}

// ---------------- all-poll device barrier: per-wg slot + every wg polls all slots ----------------
// 128 wgs. wg stores its epoch to slots[bid] (release/agent); wave 0 of every wg
// acquire-polls all 128 slots (2 per lane). Pairwise release->acquire = direct HB.
__device__ __forceinline__ void grid_bar(unsigned* __restrict__ slots, unsigned ep, int bid) {
  __syncthreads();
  if (threadIdx.x == 0)
    __hip_atomic_store(&slots[bid], ep, __ATOMIC_RELEASE, __HIP_MEMORY_SCOPE_AGENT);
  if (threadIdx.x < 64) {
    const int l = threadIdx.x;
    while (__hip_atomic_load(&slots[l], __ATOMIC_ACQUIRE, __HIP_MEMORY_SCOPE_AGENT) < ep) {}
    while (__hip_atomic_load(&slots[64 + l], __ATOMIC_ACQUIRE, __HIP_MEMORY_SCOPE_AGENT) < ep) {}
  }
  __syncthreads();
}

// ---------------- tiled bf16 GEMM: C[M,N] = A[M,K] @ B[N,K]^T ----------------
// mode 0: Cf[m*N+n] = acc (+bias[n])         (fp32 out)
// mode 1: Cb[(m&511)*32768 + (m>>9)*1024 + n] = bf16(acc)   (gates layout [t][b][n])
__global__ __launch_bounds__(256) void gemm_bt(
    const u16* __restrict__ A, const u16* __restrict__ B,
    int M, int N, int K,
    const float* __restrict__ bias,
    float* __restrict__ Cf, u16* __restrict__ Cb, int mode)
{
  __shared__ u16 a_sm[128 * 32];
  __shared__ u16 b_sm[128 * 32];
  const int tid = threadIdx.x;
  const int lane = tid & 63;
  const int wid = tid >> 6;
  const int wm = wid >> 1, wn = wid & 1;
  const int m0 = blockIdx.x * 128, n0 = blockIdx.y * 128;
  const int q = lane >> 4, l15 = lane & 15, l3 = lane & 3;

  f32x4 acc[4][4];
  #pragma unroll
  for (int i = 0; i < 4; ++i)
    #pragma unroll
    for (int j = 0; j < 4; ++j) acc[i][j] = (f32x4){0.f, 0.f, 0.f, 0.f};

  for (int kk = 0; kk < K; kk += 32) {
    __syncthreads();
    #pragma unroll
    for (int p = 0; p < 2; ++p) {
      int idx = p * 256 + tid;
      int r = idx >> 2, cch = idx & 3;
      *(uint4*)&a_sm[r * 32 + ((cch ^ (r & 3)) * 8)] =
          *(const uint4*)&A[(size_t)(m0 + r) * K + kk + cch * 8];
      *(uint4*)&b_sm[r * 32 + ((cch ^ (r & 3)) * 8)] =
          *(const uint4*)&B[(size_t)(n0 + r) * K + kk + cch * 8];
    }
    __syncthreads();
    bf16x8 af[4], bfr[4];
    #pragma unroll
    for (int s = 0; s < 4; ++s) {
      int ra = wm * 64 + s * 16 + l15;
      af[s] = *(const bf16x8*)&a_sm[ra * 32 + ((q ^ l3) * 8)];
      int rb = wn * 64 + s * 16 + l15;
      bfr[s] = *(const bf16x8*)&b_sm[rb * 32 + ((q ^ l3) * 8)];
    }
    #pragma unroll
    for (int si = 0; si < 4; ++si)
      #pragma unroll
      for (int sj = 0; sj < 4; ++sj)
        acc[si][sj] = __builtin_amdgcn_mfma_f32_16x16x32_bf16(af[si], bfr[sj], acc[si][sj], 0, 0, 0);
  }

  #pragma unroll
  for (int si = 0; si < 4; ++si)
    #pragma unroll
    for (int sj = 0; sj < 4; ++sj)
      #pragma unroll
      for (int e = 0; e < 4; ++e) {
        int m = m0 + wm * 64 + si * 16 + q * 4 + e;
        int n = n0 + wn * 64 + sj * 16 + l15;
        float v = acc[si][sj][e];
        if (mode == 0) {
          if (bias) v += bias[n];
          Cf[(size_t)m * N + n] = v;
        } else {
          Cb[(size_t)(m & 511) * 32768 + (size_t)(m >> 9) * 1024 + n] = f2b(v);
        }
      }
}

// ---------------- persistent GRU layer: 512 steps, 2 device barriers/step ----------------
// grid = 128 wgs; wg owns outputs n in [8*bid, 8*bid+8).
// Weights staged in LDS in exact MFMA B-fragment order (conflict-free ds_read_b128).
// 4 waves: wid = kh*2+bh; kh = K-half (0: k<512, 1: k>=512), bh = batch half.
// Waves kh==1 dump partials to LDS; waves kh==0 reduce + epilogue.
__global__ __launch_bounds__(256, 1) void gru_layer(
    const u16* __restrict__ Wh,                      // [3][1024][1024] bf16 (z,r,g)
    const float* __restrict__ bz, const float* __restrict__ br, const float* __restrict__ bg,
    const u16* __restrict__ gz, const u16* __restrict__ gr, const u16* __restrict__ gg, // [512][32][1024]
    const float* __restrict__ h0,                    // + l*1024, batch stride 2048
    float* __restrict__ h32, u16* __restrict__ hb, u16* __restrict__ rhb, // 32x1024 each
    u16* __restrict__ seq,                           // [b][t][n] bf16
    float* __restrict__ hT,                          // + l*1024, batch stride 2048
    unsigned* __restrict__ slots)
{
  __shared__ u16 zr_frag[32 * 512];                  // [ks][lane]*8 elems = 32 KB
  __shared__ u16 g_frag[32 * 512];                   // 32 KB
  __shared__ float z_sm[32 * 8];
  __shared__ f32x4 psum[128];                        // K-half-1 partials

  const int tid = threadIdx.x;
  const int lane = tid & 63;
  const int wid = tid >> 6;
  const int bid = blockIdx.x;
  const int nb = bid * 8;
  const int q = lane >> 4;
  const int c15 = lane & 15;
  const int kh = wid >> 1;                           // K half
  const int bh = wid & 1;                            // batch half

  // ---- stage weights into LDS in B-fragment order ----
  // frag element (ks, lane=lq*16+lc, j) = Wh[gate][nb + (lc&7)][ks*32 + lq*8 + j]
  for (int cidx = tid; cidx < 2048; cidx += 256) {
    int ks = cidx >> 6;
    int l = cidx & 63;
    int lq = l >> 4, lc = l & 15;
    int gate = (lc < 8) ? 0 : 1;                     // z | r
    const u16* src = Wh + (size_t)gate * 1048576 + (size_t)(nb + (lc & 7)) * 1024 + ks * 32 + lq * 8;
    *(uint4*)&zr_frag[cidx * 8] = *(const uint4*)src;
    const u16* srcg = Wh + (size_t)2 * 1048576 + (size_t)(nb + (lc & 7)) * 1024 + ks * 32 + lq * 8;
    *(uint4*)&g_frag[cidx * 8] = *(const uint4*)srcg;
  }
  // ---- init h state (each wg writes a distinct 256-elem span) ----
  {
    int i = bid * 256 + tid;                         // 0..32767
    int b = i >> 10, n = i & 1023;
    float v = h0[b * 2048 + n];
    h32[i] = v;
    hb[i] = f2b(v);
  }

  // per-lane epilogue constants (used by kh==0 waves)
  const int nl = c15 & 7;
  const int n_own = nb + nl;
  const bool isr = c15 >= 8;
  const float bias1 = isr ? br[n_own] : bz[n_own];
  const float bias2 = bg[n_own];

  unsigned ep = 0;
  grid_bar(slots, ++ep, bid);

  const int ks0 = kh * 16;

  for (int t = 0; t < 512; ++t) {
    // ---------- phase 1: z, r ----------
    {
      // prefetch epilogue operands (overlap with MFMA chain)
      float g1[4], ho1[4];
      if (kh == 0) {
        const u16* gin = (isr ? gr : gz) + (size_t)t * 32768 + n_own;
        #pragma unroll
        for (int e = 0; e < 4; ++e) {
          int b = bh * 16 + q * 4 + e;
          g1[e] = b2f(gin[b * 1024]);
          ho1[e] = h32[b * 1024 + n_own];
        }
      }
      const bf16x8* ap = (const bf16x8*)(hb + (size_t)(bh * 16 + c15) * 1024);
      f32x4 acc = {0.f, 0.f, 0.f, 0.f};
      #pragma unroll
      for (int i = 0; i < 16; ++i) {
        int ks = ks0 + i;
        bf16x8 af = ap[ks * 4 + q];
        bf16x8 bf = *(const bf16x8*)&zr_frag[ks * 512 + lane * 8];
        acc = __builtin_amdgcn_mfma_f32_16x16x32_bf16(af, bf, acc, 0, 0, 0);
      }
      if (kh == 1) psum[bh * 64 + lane] = acc;
      __syncthreads();
      if (kh == 0) {
        f32x4 o = psum[bh * 64 + lane];
        #pragma unroll
        for (int e = 0; e < 4; ++e) {
          int b = bh * 16 + q * 4 + e;
          float pre = acc[e] + o[e] + bias1 + g1[e];
          float s = 1.f / (1.f + __expf(-pre));
          if (isr) rhb[b * 1024 + n_own] = f2b(s * ho1[e]);
          else     z_sm[b * 8 + nl] = s;
        }
      }
    }
    grid_bar(slots, ++ep, bid);
    // ---------- phase 2: g, h' ----------
    {
      float g2[4], ho2[4];
      if (kh == 0 && !isr) {
        const u16* gin = gg + (size_t)t * 32768 + n_own;
        #pragma unroll
        for (int e = 0; e < 4; ++e) {
          int b = bh * 16 + q * 4 + e;
          g2[e] = b2f(gin[b * 1024]);
          ho2[e] = h32[b * 1024 + n_own];
        }
      }
      const bf16x8* ap = (const bf16x8*)(rhb + (size_t)(bh * 16 + c15) * 1024);
      f32x4 acc = {0.f, 0.f, 0.f, 0.f};
      #pragma unroll
      for (int i = 0; i < 16; ++i) {
        int ks = ks0 + i;
        bf16x8 af = ap[ks * 4 + q];
        bf16x8 bf = *(const bf16x8*)&g_frag[ks * 512 + lane * 8];
        acc = __builtin_amdgcn_mfma_f32_16x16x32_bf16(af, bf, acc, 0, 0, 0);
      }
      if (kh == 1) psum[bh * 64 + lane] = acc;
      __syncthreads();
      if (kh == 0 && !isr) {
        f32x4 o = psum[bh * 64 + lane];
        #pragma unroll
        for (int e = 0; e < 4; ++e) {
          int b = bh * 16 + q * 4 + e;
          float pre = acc[e] + o[e] + bias2 + g2[e];
          float ex = __expf(2.f * pre);
          float gv = 1.f - 2.f / (ex + 1.f);          // tanh, overflow-safe
          float z = z_sm[b * 8 + nl];
          float hn = z * ho2[e] + (1.f - z) * gv;
          h32[b * 1024 + n_own] = hn;
          hb[b * 1024 + n_own] = f2b(hn);
          seq[(size_t)(b * 512 + t) * 1024 + n_own] = f2b(hn);
          if (t == 511) hT[b * 2048 + n_own] = hn;
        }
      }
    }
    grid_bar(slots, ++ep, bid);
  }
}

// ---------------- host ----------------
extern "C" void kernel_launch(void* const* d_in, const int* in_sizes, int n_in,
                              void* d_out, int out_size, void* d_ws, size_t ws_size,
                              hipStream_t stream) {
  (void)in_sizes; (void)n_in; (void)out_size; (void)ws_size;
  char* ws = (char*)d_ws;
  const size_t MB = 1024ull * 1024ull;
  u16* gz   = (u16*)(ws + 0);
  u16* gr   = (u16*)(ws + 32 * MB);
  u16* gg   = (u16*)(ws + 64 * MB);
  u16* seq0 = (u16*)(ws + 96 * MB);
  u16* seq1 = (u16*)(ws + 128 * MB);
  u16* xb   = (u16*)(ws + 160 * MB);
  u16* Wh0  = (u16*)(ws + 164 * MB);
  u16* Wh1  = (u16*)(ws + 170 * MB);
  u16* Wx0  = (u16*)(ws + 176 * MB);
  u16* Wx1  = (u16*)(ws + 177 * MB);
  u16* Wyb  = (u16*)(ws + 183 * MB);
  float* h32 = (float*)(ws + 184 * MB);
  u16* hb   = (u16*)(ws + 184 * MB + 128 * 1024);
  u16* rhb  = (u16*)(ws + 184 * MB + 192 * 1024);
  unsigned* sync0 = (unsigned*)(ws + 184 * MB + 256 * 1024);   // 128 slots
  unsigned* sync1 = sync0 + 256;                               // 128 slots (1 KB apart)

  hipMemsetAsync(sync0, 0, 2048, stream);

  auto cast = [&](const void* in, u16* out, int n) {
    cast_f32_bf16<<<(n + 255) / 256, 256, 0, stream>>>((const float*)in, out, n);
  };
  cast(d_in[0], xb, 2097152);                               // x
  cast(d_in[3],  Wh0 + 0,       1048576);                   // Whz0
  cast(d_in[6],  Wh0 + 1048576, 1048576);                   // Whr0
  cast(d_in[9],  Wh0 + 2097152, 1048576);                   // Whg0
  cast(d_in[12], Wh1 + 0,       1048576);                   // Whz1
  cast(d_in[15], Wh1 + 1048576, 1048576);                   // Whr1
  cast(d_in[18], Wh1 + 2097152, 1048576);                   // Whg1
  cast(d_in[2],  Wx0 + 0,      131072);                     // Wxz0
  cast(d_in[5],  Wx0 + 131072, 131072);                     // Wxr0
  cast(d_in[8],  Wx0 + 262144, 131072);                     // Wxg0
  cast(d_in[11], Wx1 + 0,       1048576);                   // Wxz1
  cast(d_in[14], Wx1 + 1048576, 1048576);                   // Wxr1
  cast(d_in[17], Wx1 + 2097152, 1048576);                   // Wxg1
  cast(d_in[20], Wyb, 131072);                              // Wy

  dim3 blk(256);
  dim3 gP(128, 8);
  // layer-0 input projections (M=16384, N=1024, K=128) -> gates [t][b][n] bf16
  gemm_bt<<<gP, blk, 0, stream>>>(xb, Wx0 + 0,      16384, 1024, 128, nullptr, nullptr, gz, 1);
  gemm_bt<<<gP, blk, 0, stream>>>(xb, Wx0 + 131072, 16384, 1024, 128, nullptr, nullptr, gr, 1);
  gemm_bt<<<gP, blk, 0, stream>>>(xb, Wx0 + 262144, 16384, 1024, 128, nullptr, nullptr, gg, 1);

  float* y_out = (float*)d_out;
  float* hid = y_out + 2097152;                             // hidden (32,2,1024)

  gru_layer<<<128, blk, 0, stream>>>(Wh0,
      (const float*)d_in[4], (const float*)d_in[7], (const float*)d_in[10],
      gz, gr, gg, (const float*)d_in[1] + 0,
      h32, hb, rhb, seq0, hid + 0, sync0);

  // layer-1 input projections (K=1024)
  gemm_bt<<<gP, blk, 0, stream>>>(seq0, Wx1 + 0,       16384, 1024, 1024, nullptr, nullptr, gz, 1);
  gemm_bt<<<gP, blk, 0, stream>>>(seq0, Wx1 + 1048576, 16384, 1024, 1024, nullptr, nullptr, gr, 1);
  gemm_bt<<<gP, blk, 0, stream>>>(seq0, Wx1 + 2097152, 16384, 1024, 1024, nullptr, nullptr, gg, 1);

  gru_layer<<<128, blk, 0, stream>>>(Wh1,
      (const float*)d_in[13], (const float*)d_in[16], (const float*)d_in[19],
      gz, gr, gg, (const float*)d_in[1] + 1024,
      h32, hb, rhb, seq1, hid + 1024, sync1);

  // output projection y = seq1 @ Wy^T + by  (M=16384, N=128, K=1024), fp32 out
  dim3 gY(128, 1);
  gemm_bt<<<gY, blk, 0, stream>>>(seq1, Wyb, 16384, 128, 1024, (const float*)d_in[21], y_out, nullptr, 0);
}

// Round 4
// 17667.274 us; speedup vs baseline: 1.4016x; 1.2116x over previous
//
#include <hip/hip_runtime.h>

typedef unsigned short u16;
typedef unsigned int u32;
typedef unsigned long long u64;
typedef __bf16 bf16x8 __attribute__((ext_vector_type(8)));
typedef float f32x4 __attribute__((ext_vector_type(4)));

__device__ __forceinline__ u16 f2b(float f) {
  unsigned u = __float_as_uint(f);
  return (u16)((u + 0x7fffu + ((u >> 16) & 1u)) >> 16);
}
__device__ __forceinline__ float b2f(u16 h) {
  return __uint_as_float(((unsigned)h) << 16);
}

// LLC-coherent (agent-scope, relaxed => no cache-maintenance fences) accessors
__device__ __forceinline__ void st_u32_llc(u32* p, u32 v) {
  __hip_atomic_store(p, v, __ATOMIC_RELAXED, __HIP_MEMORY_SCOPE_AGENT);
}
__device__ __forceinline__ u32 ld_u32_llc(const u32* p) {
  return __hip_atomic_load(p, __ATOMIC_RELAXED, __HIP_MEMORY_SCOPE_AGENT);
}
__device__ __forceinline__ bf16x8 ld_frag_llc(const u16* p) {
  union { u64 q[2]; bf16x8 v; } u;
  u.q[0] = __hip_atomic_load((const u64*)p,     __ATOMIC_RELAXED, __HIP_MEMORY_SCOPE_AGENT);
  u.q[1] = __hip_atomic_load((const u64*)p + 1, __ATOMIC_RELAXED, __HIP_MEMORY_SCOPE_AGENT);
  return u.v;
}

// ---------------- generic fp32 -> bf16 cast ----------------
__global__ void cast_f32_bf16(const float* __restrict__ in, u16* __restrict__ out, int n) {
  int i = blockIdx.x * 256 + threadIdx.x;
  if (i < n) out[i] = f2b(in[i]);
}

// ---------------- publish + fence-free all-poll barrier ----------------
// If gbase != nullptr: wave 0 publishes 128 u32 words from sm[] to
// gbase[(w>>2)*512 + (w&3)] (b-major h-state scatter) via sc1 stores, drains
// vmcnt, then stores its slot. Every wg polls all 128 slots (relaxed).
// Ordering: data sc1-stores retire to LLC before slot store (program order +
// vmcnt drain in the SAME wave); consumers poll slot then sc1-load data.
__device__ __forceinline__ void publish_bar(u32* gbase, const u32* sm,
                                            unsigned* slots, unsigned ep, int bid) {
  __syncthreads();                  // all waves arrived; each drained its own vmcnt
  if (threadIdx.x < 64) {
    const int l = threadIdx.x;
    if (gbase) {
      #pragma unroll
      for (int w = l; w < 128; w += 64)
        st_u32_llc(&gbase[(w >> 2) * 512 + (w & 3)], sm[w]);
    }
    asm volatile("s_waitcnt vmcnt(0)" ::: "memory");
    if (l == 0)
      __hip_atomic_store(&slots[bid], ep, __ATOMIC_RELAXED, __HIP_MEMORY_SCOPE_AGENT);
    while (__hip_atomic_load(&slots[l], __ATOMIC_RELAXED, __HIP_MEMORY_SCOPE_AGENT) < ep) {}
    while (__hip_atomic_load(&slots[64 + l], __ATOMIC_RELAXED, __HIP_MEMORY_SCOPE_AGENT) < ep) {}
  }
  __syncthreads();
}

// ---------------- tiled bf16 GEMM: C[M,N] = A[M,K] @ B[N,K]^T ----------------
// mode 0: Cf[m*N+n] = acc (+bias[n])         (fp32 out)
// mode 1: Cb[(m&511)*32768 + (m>>9)*1024 + n] = bf16(acc)   (gates layout [t][b][n])
__global__ __launch_bounds__(256) void gemm_bt(
    const u16* __restrict__ A, const u16* __restrict__ B,
    int M, int N, int K,
    const float* __restrict__ bias,
    float* __restrict__ Cf, u16* __restrict__ Cb, int mode)
{
  __shared__ u16 a_sm[128 * 32];
  __shared__ u16 b_sm[128 * 32];
  const int tid = threadIdx.x;
  const int lane = tid & 63;
  const int wid = tid >> 6;
  const int wm = wid >> 1, wn = wid & 1;
  const int m0 = blockIdx.x * 128, n0 = blockIdx.y * 128;
  const int q = lane >> 4, l15 = lane & 15, l3 = lane & 3;

  f32x4 acc[4][4];
  #pragma unroll
  for (int i = 0; i < 4; ++i)
    #pragma unroll
    for (int j = 0; j < 4; ++j) acc[i][j] = (f32x4){0.f, 0.f, 0.f, 0.f};

  for (int kk = 0; kk < K; kk += 32) {
    __syncthreads();
    #pragma unroll
    for (int p = 0; p < 2; ++p) {
      int idx = p * 256 + tid;
      int r = idx >> 2, cch = idx & 3;
      *(uint4*)&a_sm[r * 32 + ((cch ^ (r & 3)) * 8)] =
          *(const uint4*)&A[(size_t)(m0 + r) * K + kk + cch * 8];
      *(uint4*)&b_sm[r * 32 + ((cch ^ (r & 3)) * 8)] =
          *(const uint4*)&B[(size_t)(n0 + r) * K + kk + cch * 8];
    }
    __syncthreads();
    bf16x8 af[4], bfr[4];
    #pragma unroll
    for (int s = 0; s < 4; ++s) {
      int ra = wm * 64 + s * 16 + l15;
      af[s] = *(const bf16x8*)&a_sm[ra * 32 + ((q ^ l3) * 8)];
      int rb = wn * 64 + s * 16 + l15;
      bfr[s] = *(const bf16x8*)&b_sm[rb * 32 + ((q ^ l3) * 8)];
    }
    #pragma unroll
    for (int si = 0; si < 4; ++si)
      #pragma unroll
      for (int sj = 0; sj < 4; ++sj)
        acc[si][sj] = __builtin_amdgcn_mfma_f32_16x16x32_bf16(af[si], bfr[sj], acc[si][sj], 0, 0, 0);
  }

  #pragma unroll
  for (int si = 0; si < 4; ++si)
    #pragma unroll
    for (int sj = 0; sj < 4; ++sj)
      #pragma unroll
      for (int e = 0; e < 4; ++e) {
        int m = m0 + wm * 64 + si * 16 + q * 4 + e;
        int n = n0 + wn * 64 + sj * 16 + l15;
        float v = acc[si][sj][e];
        if (mode == 0) {
          if (bias) v += bias[n];
          Cf[(size_t)m * N + n] = v;
        } else {
          Cb[(size_t)(m & 511) * 32768 + (size_t)(m >> 9) * 1024 + n] = f2b(v);
        }
      }
}

// ---------------- persistent GRU layer: 512 steps, 2 fence-free barriers/step ----------------
// grid = 128 wgs; wg owns outputs n in [8*bid, 8*bid+8).
// Weights in LDS in exact MFMA B-fragment order (conflict-free ds_read_b128).
// 4 waves: wid = kh*2+bh; kh = K-half, bh = batch half. kh==1 dumps partials to
// LDS psum; kh==0 reduces + epilogue. Shared h-state moves ONLY via sc1
// (relaxed agent atomic) accesses; no acquire/release fences anywhere.
__global__ __launch_bounds__(256, 1) void gru_layer(
    const u16* __restrict__ Wh,                      // [3][1024][1024] bf16 (z,r,g)
    const float* __restrict__ bz, const float* __restrict__ br, const float* __restrict__ bg,
    const u16* __restrict__ gz, const u16* __restrict__ gr, const u16* __restrict__ gg, // [512][32][1024]
    const float* __restrict__ h0,                    // + l*1024, batch stride 2048
    float* __restrict__ h32, u16* __restrict__ hb, u16* __restrict__ rhb, // h32 wg-private slice
    u16* __restrict__ seq,                           // [b][t][n] bf16
    float* __restrict__ hT,                          // + l*1024, batch stride 2048
    unsigned* __restrict__ slots)
{
  __shared__ u16 zr_frag[32 * 512];                  // 32 KB, B-frag order
  __shared__ u16 g_frag[32 * 512];                   // 32 KB
  __shared__ float z_sm[32 * 8];
  __shared__ f32x4 psum[128];
  __shared__ u16 pub_sm[32 * 8];                     // staging for rh / h publish (512 B)

  const int tid = threadIdx.x;
  const int lane = tid & 63;
  const int wid = tid >> 6;
  const int bid = blockIdx.x;
  const int nb = bid * 8;
  const int q = lane >> 4;
  const int c15 = lane & 15;
  const int kh = wid >> 1;
  const int bh = wid & 1;

  // ---- stage weights into LDS in B-fragment order ----
  for (int cidx = tid; cidx < 2048; cidx += 256) {
    int ks = cidx >> 6;
    int l = cidx & 63;
    int lq = l >> 4, lc = l & 15;
    int gate = (lc < 8) ? 0 : 1;                     // z | r
    const u16* src = Wh + (size_t)gate * 1048576 + (size_t)(nb + (lc & 7)) * 1024 + ks * 32 + lq * 8;
    *(uint4*)&zr_frag[cidx * 8] = *(const uint4*)src;
    const u16* srcg = Wh + (size_t)2 * 1048576 + (size_t)(nb + (lc & 7)) * 1024 + ks * 32 + lq * 8;
    *(uint4*)&g_frag[cidx * 8] = *(const uint4*)srcg;
  }
  // ---- init h state: own n-slice only ----
  if (tid < 128) {
    int b = tid >> 2, p = tid & 3;
    int n0i = nb + p * 2;
    float v0 = h0[b * 2048 + n0i], v1 = h0[b * 2048 + n0i + 1];
    u32 w = (u32)f2b(v0) | ((u32)f2b(v1) << 16);
    st_u32_llc((u32*)hb + b * 512 + (nb >> 1) + p, w);
  }
  {
    int b = tid >> 3, n = nb + (tid & 7);
    h32[b * 1024 + n] = h0[b * 2048 + n];            // wg-private: normal store
  }

  // per-lane epilogue constants
  const int nl = c15 & 7;
  const int n_own = nb + nl;
  const bool isr = c15 >= 8;
  const float bias1 = isr ? br[n_own] : bz[n_own];
  const float bias2 = bg[n_own];

  u32* grh = (u32*)rhb + (nb >> 1);                  // publish bases (b-major scatter)
  u32* ghb = (u32*)hb + (nb >> 1);

  unsigned ep = 0;
  publish_bar(nullptr, nullptr, slots, ++ep, bid);

  const int ks0 = kh * 16;

  for (int t = 0; t < 512; ++t) {
    // ---------- phase 1: z, r ----------
    {
      float g1[4], ho1[4];
      if (kh == 0) {
        const u16* gin = (isr ? gr : gz) + (size_t)t * 32768 + n_own;
        #pragma unroll
        for (int e = 0; e < 4; ++e) {
          int b = bh * 16 + q * 4 + e;
          g1[e] = b2f(gin[b * 1024]);
          ho1[e] = h32[b * 1024 + n_own];            // wg-private: normal load
        }
      }
      const u16* arow = hb + (size_t)(bh * 16 + c15) * 1024;
      f32x4 acc = {0.f, 0.f, 0.f, 0.f};
      #pragma unroll
      for (int i = 0; i < 16; ++i) {
        int ks = ks0 + i;
        bf16x8 af = ld_frag_llc(arow + ks * 32 + q * 8);
        bf16x8 bf = *(const bf16x8*)&zr_frag[ks * 512 + lane * 8];
        acc = __builtin_amdgcn_mfma_f32_16x16x32_bf16(af, bf, acc, 0, 0, 0);
      }
      if (kh == 1) psum[bh * 64 + lane] = acc;
      __syncthreads();
      if (kh == 0) {
        f32x4 o = psum[bh * 64 + lane];
        #pragma unroll
        for (int e = 0; e < 4; ++e) {
          int b = bh * 16 + q * 4 + e;
          float pre = acc[e] + o[e] + bias1 + g1[e];
          float s = 1.f / (1.f + __expf(-pre));
          if (isr) pub_sm[b * 8 + nl] = f2b(s * ho1[e]);
          else     z_sm[b * 8 + nl] = s;
        }
      }
    }
    publish_bar(grh, (const u32*)pub_sm, slots, ++ep, bid);
    // ---------- phase 2: g, h' ----------
    {
      float g2[4], ho2[4];
      if (kh == 0 && !isr) {
        const u16* gin = gg + (size_t)t * 32768 + n_own;
        #pragma unroll
        for (int e = 0; e < 4; ++e) {
          int b = bh * 16 + q * 4 + e;
          g2[e] = b2f(gin[b * 1024]);
          ho2[e] = h32[b * 1024 + n_own];
        }
      }
      const u16* arow = rhb + (size_t)(bh * 16 + c15) * 1024;
      f32x4 acc = {0.f, 0.f, 0.f, 0.f};
      #pragma unroll
      for (int i = 0; i < 16; ++i) {
        int ks = ks0 + i;
        bf16x8 af = ld_frag_llc(arow + ks * 32 + q * 8);
        bf16x8 bf = *(const bf16x8*)&g_frag[ks * 512 + lane * 8];
        acc = __builtin_amdgcn_mfma_f32_16x16x32_bf16(af, bf, acc, 0, 0, 0);
      }
      if (kh == 1) psum[bh * 64 + lane] = acc;
      __syncthreads();
      if (kh == 0 && !isr) {
        f32x4 o = psum[bh * 64 + lane];
        #pragma unroll
        for (int e = 0; e < 4; ++e) {
          int b = bh * 16 + q * 4 + e;
          float pre = acc[e] + o[e] + bias2 + g2[e];
          float ex = __expf(2.f * pre);
          float gv = 1.f - 2.f / (ex + 1.f);          // tanh, overflow-safe
          float z = z_sm[b * 8 + nl];
          float hn = z * ho2[e] + (1.f - z) * gv;
          h32[b * 1024 + n_own] = hn;                 // wg-private
          pub_sm[b * 8 + nl] = f2b(hn);               // -> hb via publish
          seq[(size_t)(b * 512 + t) * 1024 + n_own] = f2b(hn);
          if (t == 511) hT[b * 2048 + n_own] = hn;
        }
      }
    }
    publish_bar(ghb, (const u32*)pub_sm, slots, ++ep, bid);
  }
}

// ---------------- host ----------------
extern "C" void kernel_launch(void* const* d_in, const int* in_sizes, int n_in,
                              void* d_out, int out_size, void* d_ws, size_t ws_size,
                              hipStream_t stream) {
  (void)in_sizes; (void)n_in; (void)out_size; (void)ws_size;
  char* ws = (char*)d_ws;
  const size_t MB = 1024ull * 1024ull;
  u16* gz   = (u16*)(ws + 0);
  u16* gr   = (u16*)(ws + 32 * MB);
  u16* gg   = (u16*)(ws + 64 * MB);
  u16* seq0 = (u16*)(ws + 96 * MB);
  u16* seq1 = (u16*)(ws + 128 * MB);
  u16* xb   = (u16*)(ws + 160 * MB);
  u16* Wh0  = (u16*)(ws + 164 * MB);
  u16* Wh1  = (u16*)(ws + 170 * MB);
  u16* Wx0  = (u16*)(ws + 176 * MB);
  u16* Wx1  = (u16*)(ws + 177 * MB);
  u16* Wyb  = (u16*)(ws + 183 * MB);
  float* h32 = (float*)(ws + 184 * MB);
  u16* hb   = (u16*)(ws + 184 * MB + 128 * 1024);
  u16* rhb  = (u16*)(ws + 184 * MB + 192 * 1024);
  unsigned* sync0 = (unsigned*)(ws + 184 * MB + 256 * 1024);   // 128 slots
  unsigned* sync1 = sync0 + 256;                               // 128 slots

  hipMemsetAsync(sync0, 0, 2048, stream);

  auto cast = [&](const void* in, u16* out, int n) {
    cast_f32_bf16<<<(n + 255) / 256, 256, 0, stream>>>((const float*)in, out, n);
  };
  cast(d_in[0], xb, 2097152);                               // x
  cast(d_in[3],  Wh0 + 0,       1048576);                   // Whz0
  cast(d_in[6],  Wh0 + 1048576, 1048576);                   // Whr0
  cast(d_in[9],  Wh0 + 2097152, 1048576);                   // Whg0
  cast(d_in[12], Wh1 + 0,       1048576);                   // Whz1
  cast(d_in[15], Wh1 + 1048576, 1048576);                   // Whr1
  cast(d_in[18], Wh1 + 2097152, 1048576);                   // Whg1
  cast(d_in[2],  Wx0 + 0,      131072);                     // Wxz0
  cast(d_in[5],  Wx0 + 131072, 131072);                     // Wxr0
  cast(d_in[8],  Wx0 + 262144, 131072);                     // Wxg0
  cast(d_in[11], Wx1 + 0,       1048576);                   // Wxz1
  cast(d_in[14], Wx1 + 1048576, 1048576);                   // Wxr1
  cast(d_in[17], Wx1 + 2097152, 1048576);                   // Wxg1
  cast(d_in[20], Wyb, 131072);                              // Wy

  dim3 blk(256);
  dim3 gP(128, 8);
  // layer-0 input projections (M=16384, N=1024, K=128) -> gates [t][b][n] bf16
  gemm_bt<<<gP, blk, 0, stream>>>(xb, Wx0 + 0,      16384, 1024, 128, nullptr, nullptr, gz, 1);
  gemm_bt<<<gP, blk, 0, stream>>>(xb, Wx0 + 131072, 16384, 1024, 128, nullptr, nullptr, gr, 1);
  gemm_bt<<<gP, blk, 0, stream>>>(xb, Wx0 + 262144, 16384, 1024, 128, nullptr, nullptr, gg, 1);

  float* y_out = (float*)d_out;
  float* hid = y_out + 2097152;                             // hidden (32,2,1024)

  gru_layer<<<128, blk, 0, stream>>>(Wh0,
      (const float*)d_in[4], (const float*)d_in[7], (const float*)d_in[10],
      gz, gr, gg, (const float*)d_in[1] + 0,
      h32, hb, rhb, seq0, hid + 0, sync0);

  // layer-1 input projections (K=1024)
  gemm_bt<<<gP, blk, 0, stream>>>(seq0, Wx1 + 0,       16384, 1024, 1024, nullptr, nullptr, gz, 1);
  gemm_bt<<<gP, blk, 0, stream>>>(seq0, Wx1 + 1048576, 16384, 1024, 1024, nullptr, nullptr, gr, 1);
  gemm_bt<<<gP, blk, 0, stream>>>(seq0, Wx1 + 2097152, 16384, 1024, 1024, nullptr, nullptr, gg, 1);

  gru_layer<<<128, blk, 0, stream>>>(Wh1,
      (const float*)d_in[13], (const float*)d_in[16], (const float*)d_in[19],
      gz, gr, gg, (const float*)d_in[1] + 1024,
      h32, hb, rhb, seq1, hid + 1024, sync1);

  // output projection y = seq1 @ Wy^T + by  (M=16384, N=128, K=1024), fp32 out
  dim3 gY(128, 1);
  gemm_bt<<<gY, blk, 0, stream>>>(seq1, Wyb, 16384, 128, 1024, (const float*)d_in[21], y_out, nullptr, 0);
}